// Round 2
// baseline (523.480 us; speedup 1.0000x reference)
//
#include <hip/hip_runtime.h>

typedef __attribute__((ext_vector_type(8))) short  shortx8;  // 8 bf16 (MFMA A/B frag)
typedef __attribute__((ext_vector_type(4))) short  shortx4;  // 4 bf16 (8 B)
typedef __attribute__((ext_vector_type(4))) float  floatx4;  // MFMA C/D

#define I_SZ 64
#define K_SZ 1024
#define IK   65536        // stride (floats) of b in x / o in w
#define OI   65536        // stride (floats) of b in out
#define BK   128          // k per LDS tile
#define NKT  (K_SZ / BK)  // 8
#define LROW 256          // LDS bytes per tile row (BK * 2B bf16)

// fp32 -> bf16 round-to-nearest-even
__device__ __forceinline__ unsigned short f2bf(float f) {
    unsigned int u = __builtin_bit_cast(unsigned int, f);
    u += 0x7fffu + ((u >> 16) & 1u);
    return (unsigned short)(u >> 16);
}

__device__ __forceinline__ shortx4 cvt4(float4 a) {
    shortx4 r;
    r[0] = (short)f2bf(a.x); r[1] = (short)f2bf(a.y);
    r[2] = (short)f2bf(a.z); r[3] = (short)f2bf(a.w);
    return r;
}

// grid = 512 (64 i-slices x 8 o-tiles), block = 256 (4 waves, 2x2, wave tile 64x64)
// LDS-staged bf16 GEMM tiles: A,B = [128][BK] bf16, XOR-swizzled, single-buffered.
// 64 KB LDS/block -> 2 blocks/CU; co-resident blocks overlap stage vs compute.
__global__ __launch_bounds__(256, 2) void factlin_mfma2(
    const float* __restrict__ x, const float* __restrict__ w,
    const float* __restrict__ bias, float* __restrict__ out)
{
    __shared__ __align__(16) char lA[128 * LROW];   // 32 KB
    __shared__ __align__(16) char lB[128 * LROW];   // 32 KB

    const int wg   = blockIdx.x;
    const int nt   = wg & 7;    // o-tile; same nt -> same XCD (output line merge in L2)
    const int i    = wg >> 3;   // factor index
    const int tid  = threadIdx.x;
    const int lane = tid & 63;
    const int wid  = tid >> 6;
    const int wm   = wid >> 1;          // wave row (b)
    const int wn   = wid & 1;           // wave col (o)
    const int lrow = lane & 15;
    const int g    = lane >> 4;         // k sub-group within fragment

    const float* gA = x + i * K_SZ;                     // + row*IK + kt*BK + col
    const float* gB = w + (nt * 128) * IK + i * K_SZ;

    floatx4 acc[4][4] = {};

    #pragma unroll 1
    for (int kt = 0; kt < NKT; ++kt) {
        __syncthreads();   // previous compute phase done reading LDS

        // ---- stage: 32 float4 per thread (16 A + 16 B), groups of 8 ----
        // chunk c in [0,4096): row = c>>5 (tile row), col4 = c&31 (float4 within BK)
        // global: 512-B contiguous per row-slice; wave-instr covers 2 rows = 2x512B.
        float4 buf[8];
        #pragma unroll
        for (int grp = 0; grp < 2; ++grp) {
            #pragma unroll
            for (int e = 0; e < 8; ++e) {
                const int c = (grp * 8 + e) * 256 + tid;
                buf[e] = *(const float4*)(gA + (c >> 5) * IK + kt * BK + (c & 31) * 4);
            }
            #pragma unroll
            for (int e = 0; e < 8; ++e) {
                const int c = (grp * 8 + e) * 256 + tid;
                const int row = c >> 5;
                const int off = row * LROW + (((c & 31) * 8) ^ ((row & 7) << 4));
                *(shortx4*)(lA + off) = cvt4(buf[e]);
            }
        }
        #pragma unroll
        for (int grp = 0; grp < 2; ++grp) {
            #pragma unroll
            for (int e = 0; e < 8; ++e) {
                const int c = (grp * 8 + e) * 256 + tid;
                buf[e] = *(const float4*)(gB + (c >> 5) * IK + kt * BK + (c & 31) * 4);
            }
            #pragma unroll
            for (int e = 0; e < 8; ++e) {
                const int c = (grp * 8 + e) * 256 + tid;
                const int row = c >> 5;
                const int off = row * LROW + (((c & 31) * 8) ^ ((row & 7) << 4));
                *(shortx4*)(lB + off) = cvt4(buf[e]);
            }
        }

        __syncthreads();   // staged tile visible

        // ---- compute: 4 k-steps x (4 A-frags + 4 B-frags + 16 MFMA) ----
        #pragma unroll
        for (int ks = 0; ks < 4; ++ks) {
            shortx8 af[4], bf[4];
            #pragma unroll
            for (int mi = 0; mi < 4; ++mi) {
                const int row = wm * 64 + mi * 16 + lrow;
                const int off = row * LROW + ((ks * 64 + g * 16) ^ ((row & 7) << 4));
                af[mi] = *(const shortx8*)(lA + off);
            }
            #pragma unroll
            for (int ni = 0; ni < 4; ++ni) {
                const int row = wn * 64 + ni * 16 + lrow;
                const int off = row * LROW + ((ks * 64 + g * 16) ^ ((row & 7) << 4));
                bf[ni] = *(const shortx8*)(lB + off);
            }
            #pragma unroll
            for (int mi = 0; mi < 4; ++mi)
                #pragma unroll
                for (int ni = 0; ni < 4; ++ni)
                    acc[mi][ni] = __builtin_amdgcn_mfma_f32_16x16x32_bf16(
                        af[mi], bf[ni], acc[mi][ni], 0, 0, 0);
        }
    }

    // ---- epilogue (same scheme as round-0, verified): D col=lane&15 -> o,
    //      row=(lane>>4)*4+reg -> b ----
    const int obase = nt * 128 + wn * 64;
    float bv[4];
    #pragma unroll
    for (int ni = 0; ni < 4; ++ni)
        bv[ni] = bias[(obase + ni * 16 + lrow) * I_SZ + i];

    const int rb = wm * 64 + g * 4;
    #pragma unroll
    for (int mi = 0; mi < 4; ++mi) {
        #pragma unroll
        for (int ni = 0; ni < 4; ++ni) {
            const int ocol = obase + ni * 16 + lrow;
            float* op = out + (rb + mi * 16) * OI + ocol * I_SZ + i;
            #pragma unroll
            for (int r = 0; r < 4; ++r)
                op[r * OI] = acc[mi][ni][r] + bv[ni];
        }
    }
}

extern "C" void kernel_launch(void* const* d_in, const int* in_sizes, int n_in,
                              void* d_out, int out_size, void* d_ws, size_t ws_size,
                              hipStream_t stream) {
    const float* x  = (const float*)d_in[0];   // [128][64][1024] fp32
    const float* w  = (const float*)d_in[1];   // [1024][64][1024] fp32
    const float* b  = (const float*)d_in[2];   // [1024][64] fp32
    float* out      = (float*)d_out;           // [128][1024][64] fp32

    factlin_mfma2<<<dim3(512), dim3(256), 0, stream>>>(x, w, b, out);
}

// Round 3
// 429.149 us; speedup vs baseline: 1.2198x; 1.2198x over previous
//
#include <hip/hip_runtime.h>

typedef __attribute__((ext_vector_type(8))) short  shortx8;  // 8 bf16 (MFMA A/B frag)
typedef __attribute__((ext_vector_type(4))) short  shortx4;  // 4 bf16 (8 B)
typedef __attribute__((ext_vector_type(4))) float  floatx4;  // MFMA C/D

#define I_SZ 64
#define K_SZ 1024
#define IK   65536        // stride (floats) of b in x / o in w
#define OI   65536        // stride (floats) of b in out
#define BK   64           // k per LDS tile
#define NKT  (K_SZ / BK)  // 16
#define LROW 128          // LDS bytes per tile row (BK * 2B bf16)

// fp32 -> bf16 round-to-nearest-even
__device__ __forceinline__ unsigned short f2bf(float f) {
    unsigned int u = __builtin_bit_cast(unsigned int, f);
    u += 0x7fffu + ((u >> 16) & 1u);
    return (unsigned short)(u >> 16);
}

__device__ __forceinline__ shortx4 cvt4(float4 a) {
    shortx4 r;
    r[0] = (short)f2bf(a.x); r[1] = (short)f2bf(a.y);
    r[2] = (short)f2bf(a.z); r[3] = (short)f2bf(a.w);
    return r;
}

// grid = 512 (64 i x 8 o-tiles), block = 256 (4 waves 2x2, wave tile 64x64).
// Double-buffered bf16 LDS tiles [128][BK], XOR-swizzled. Per K-step:
//   issue 16 global loads (kt+1) -> compute on buf[cur] -> vmcnt drain ->
//   cvt+ds_write buf[cur^1] -> ONE barrier.
// Loads stay in flight under the whole compute phase (16 KB/wave).
__global__ __launch_bounds__(256, 2) void factlin_v3(
    const float* __restrict__ x, const float* __restrict__ w,
    const float* __restrict__ bias, float* __restrict__ out)
{
    __shared__ __align__(16) char lA[2][128 * LROW];   // 2 x 16 KB
    __shared__ __align__(16) char lB[2][128 * LROW];   // 2 x 16 KB

    const int wg   = blockIdx.x;
    const int nt   = wg & 7;    // o-tile; same nt -> same XCD (output line merge)
    const int i    = wg >> 3;   // factor index
    const int tid  = threadIdx.x;
    const int lane = tid & 63;
    const int wid  = tid >> 6;
    const int wm   = wid >> 1;          // wave row (b)
    const int wn   = wid & 1;           // wave col (o)
    const int lrow = lane & 15;
    const int g    = lane >> 4;

    const float* gA = x + i * K_SZ;
    const float* gB = w + (nt * 128) * IK + i * K_SZ;

    // staging decomposition: c = e*256 + tid; row = c>>4, col4 = c&15
    // per wave-instruction: 4 rows x 256 B contiguous each.
    float4 vA[8], vB[8];

    auto issue = [&](int kt) {
        #pragma unroll
        for (int e = 0; e < 8; ++e) {
            const int c = e * 256 + tid;
            vA[e] = *(const float4*)(gA + (c >> 4) * IK + kt * BK + (c & 15) * 4);
        }
        #pragma unroll
        for (int e = 0; e < 8; ++e) {
            const int c = e * 256 + tid;
            vB[e] = *(const float4*)(gB + (c >> 4) * IK + kt * BK + (c & 15) * 4);
        }
    };
    auto commit = [&](int buf) {   // vmcnt waits land here, after compute
        #pragma unroll
        for (int e = 0; e < 8; ++e) {
            const int c   = e * 256 + tid;
            const int row = c >> 4;
            const int off = row * LROW + (((c & 15) * 8) ^ ((row & 7) << 4));
            *(shortx4*)(lA[buf] + off) = cvt4(vA[e]);
            *(shortx4*)(lB[buf] + off) = cvt4(vB[e]);
        }
    };

    issue(0);
    commit(0);
    __syncthreads();

    floatx4 acc[4][4] = {};

    #pragma unroll 1
    for (int kt = 0; kt < NKT; ++kt) {
        const int cur = kt & 1;

        if (kt + 1 < NKT) issue(kt + 1);   // in flight under the MFMA phase

        #pragma unroll
        for (int ks = 0; ks < 2; ++ks) {
            shortx8 af[4], bf[4];
            #pragma unroll
            for (int mi = 0; mi < 4; ++mi) {
                const int row = wm * 64 + mi * 16 + lrow;
                const int off = row * LROW + ((ks * 64 + g * 16) ^ ((row & 7) << 4));
                af[mi] = *(const shortx8*)(lA[cur] + off);
            }
            #pragma unroll
            for (int ni = 0; ni < 4; ++ni) {
                const int row = wn * 64 + ni * 16 + lrow;
                const int off = row * LROW + ((ks * 64 + g * 16) ^ ((row & 7) << 4));
                bf[ni] = *(const shortx8*)(lB[cur] + off);
            }
            #pragma unroll
            for (int mi = 0; mi < 4; ++mi)
                #pragma unroll
                for (int ni = 0; ni < 4; ++ni)
                    acc[mi][ni] = __builtin_amdgcn_mfma_f32_16x16x32_bf16(
                        af[mi], bf[ni], acc[mi][ni], 0, 0, 0);
        }

        if (kt + 1 < NKT) commit(cur ^ 1);  // safe: reads of cur^1 retired at last barrier
        __syncthreads();
    }

    // epilogue (verified): D col = lane&15 -> o, row = (lane>>4)*4 + reg -> b
    const int obase = nt * 128 + wn * 64;
    float bv[4];
    #pragma unroll
    for (int ni = 0; ni < 4; ++ni)
        bv[ni] = bias[(obase + ni * 16 + lrow) * I_SZ + i];

    const int rb = wm * 64 + g * 4;
    #pragma unroll
    for (int mi = 0; mi < 4; ++mi) {
        #pragma unroll
        for (int ni = 0; ni < 4; ++ni) {
            const int ocol = obase + ni * 16 + lrow;
            float* op = out + (rb + mi * 16) * OI + ocol * I_SZ + i;
            #pragma unroll
            for (int r = 0; r < 4; ++r)
                op[r * OI] = acc[mi][ni][r] + bv[ni];
        }
    }
}

extern "C" void kernel_launch(void* const* d_in, const int* in_sizes, int n_in,
                              void* d_out, int out_size, void* d_ws, size_t ws_size,
                              hipStream_t stream) {
    const float* x  = (const float*)d_in[0];   // [128][64][1024] fp32
    const float* w  = (const float*)d_in[1];   // [1024][64][1024] fp32
    const float* b  = (const float*)d_in[2];   // [1024][64] fp32
    float* out      = (float*)d_out;           // [128][1024][64] fp32

    factlin_v3<<<dim3(512), dim3(256), 0, stream>>>(x, w, b, out);
}